// Round 11
// baseline (139.901 us; speedup 1.0000x reference)
//
#include <hip/hip_runtime.h>
#include <cstdint>
#include <cmath>

#define DEV __device__ __forceinline__

typedef float v4f __attribute__((ext_vector_type(4)));
typedef short v8s __attribute__((ext_vector_type(8)));

// Problem constants
// x: [8,256,48,48] f32; weight: [256,256,3,3]; off_w: [18,256,3,3]; off_b:[18];
// mask_w: [9,256,3,3]; mask_b:[9]; out: [8,256,48,48] f32
static constexpr int HW    = 48 * 48;        // 2304
static constexpr int NPOS  = 8 * HW;         // 18432

DEV float bf2f(unsigned short u) {
  unsigned int v = ((unsigned int)u) << 16;
  float f; __builtin_memcpy(&f, &v, 4); return f;
}
DEV unsigned short f2bf(float f) {
  unsigned int u; __builtin_memcpy(&u, &f, 4);
  unsigned int r = (u + 0x7fffu + ((u >> 16) & 1u)) >> 16;
  return (unsigned short)r;
}

DEV void gload16(const void* g, void* l) {
  __builtin_amdgcn_global_load_lds(
      (const __attribute__((address_space(1))) unsigned int*)g,
      (__attribute__((address_space(3))) unsigned int*)l, 16, 0, 0);
}

// ---------------- prep (fused): Wc2 + zp; wG ---------------------------------
// grid 544 x 256. Blocks 0..287: Wc2 (+zp). Blocks 288..543: wG transpose.
__global__ __launch_bounds__(256) void k_prep(const float* __restrict__ off_w,
                                              const float* __restrict__ mask_w,
                                              const float* __restrict__ weight,
                                              unsigned short* __restrict__ Wc2,
                                              unsigned short* __restrict__ zp,
                                              unsigned short* __restrict__ wG) {
  __shared__ float wrow[2304];
  int bid = blockIdx.x, tid = threadIdx.x;
  int i = bid * 256 + tid;
  if (bid < 288) {
    if (i < 256) zp[i] = 0;
    int o = i / 2304, col = i % 2304;
    int t = col >> 8, c = col & 255;
    float v = 0.f;
    if (o < 18)      v = off_w[(o * 256 + c) * 9 + t];
    else if (o < 27) v = mask_w[((o - 18) * 256 + c) * 9 + t];
    Wc2[i] = f2bf(v);
  } else {
    int co = bid - 288;
    const float* wsrc = weight + (size_t)co * 2304;
    for (int k = tid; k < 2304; k += 256) wrow[k] = wsrc[k];
    __syncthreads();
    unsigned short* dst = wG + (size_t)co * 2304;
    #pragma unroll
    for (int k = 0; k < 9; k++)
      dst[k * 256 + tid] = f2bf(wrow[tid * 9 + k]);
  }
}

// ---------------- prep: x NCHW f32 -> xT [b][hw][c] bf16 ---------------------
__global__ void k_xt(const float* __restrict__ x, unsigned short* __restrict__ xT) {
  __shared__ float tile[64][65];
  int bid = blockIdx.x;                 // b*144 + hwt*4 + ct
  int ct = bid & 3; int hwt = (bid >> 2) % 36; int b = bid / 144;
  int c0 = ct * 64, hw0 = hwt * 64;
  int tl = threadIdx.x & 63, tr = threadIdx.x >> 6;
  const float* xb = x + (size_t)(b * 256 + c0) * 2304 + hw0;
  #pragma unroll
  for (int r = 0; r < 16; r++) {
    int cr = tr + r * 4;
    tile[cr][tl] = xb[(size_t)cr * 2304 + tl];
  }
  __syncthreads();
  unsigned short* xo = xT + ((size_t)b * 2304 + hw0) * 256 + c0;
  #pragma unroll
  for (int r = 0; r < 16; r++) {
    int hr = tr + r * 4;
    xo[(size_t)hr * 256 + tl] = f2bf(tile[tl][hr]);
  }
}

// ---------------- offset/mask conv as MFMA GEMM ------------------------------
// S[32][NPOS] = Wc2[32][2304] * im2col(xT)[2304][NPOS], split-K by tap triple.
// grid (288, 3): BN=64, per chunk K=768 (3 taps x 256 ch), BK=64.
// parS layout: [kc][32][NPOS] fp32.
__global__ __launch_bounds__(256) void k_cg(const unsigned short* __restrict__ Wc2,
                                            const unsigned short* __restrict__ xT,
                                            const unsigned short* __restrict__ zp,
                                            float* __restrict__ parS) {
  __shared__ unsigned short ldsA[32 * 64];
  __shared__ unsigned short ldsB[64 * 64];
  int nt = blockIdx.x, kc = blockIdx.y;
  int n0 = nt * 64;
  int b = n0 / 2304, hw0 = n0 % 2304;         // BN=64 divides 2304: one image
  int tid = threadIdx.x, lane = tid & 63, wid = tid >> 6;
  int r = lane & 15, q = lane >> 4;
  int row0 = tid >> 3;                        // staging row (0..31)
  int sslot = (tid & 7) ^ (row0 & 7);         // pre-swizzled 16B slot

  int hwA = hw0 + row0,      hA = hwA / 48, wA = hwA % 48;   // B round 0 row
  int hwB = hw0 + row0 + 32, hB = hwB / 48, wB = hwB % 48;   // B round 1 row

  v4f acc0 = (v4f){0.f, 0.f, 0.f, 0.f};
  v4f acc1 = (v4f){0.f, 0.f, 0.f, 0.f};

  #pragma unroll
  for (int tt = 0; tt < 3; tt++) {
    int t = kc * 3 + tt;
    int dy = kc - 1, dx = tt - 1;
    int yA = hA + dy, xA = wA + dx;
    int yB = hB + dy, xB = wB + dx;
    bool vA = ((unsigned)yA < 48u) && ((unsigned)xA < 48u);
    bool vB = ((unsigned)yB < 48u) && ((unsigned)xB < 48u);
    const unsigned short* baseA2 = Wc2 + (size_t)row0 * 2304 + t * 256 + sslot * 8;
    const unsigned short* base0 = vA ? xT + ((size_t)(b * 2304 + yA * 48 + xA) * 256 + sslot * 8)
                                     : zp + sslot * 8;
    const unsigned short* base1 = vB ? xT + ((size_t)(b * 2304 + yB * 48 + xB) * 256 + sslot * 8)
                                     : zp + sslot * 8;
    #pragma unroll
    for (int cq = 0; cq < 4; cq++) {
      int c0s = cq * 64;
      __syncthreads();                        // prev tile reads done
      gload16(baseA2 + c0s, ldsA + tid * 8);
      gload16(base0  + c0s, ldsB + tid * 8);
      gload16(base1  + c0s, ldsB + 2048 + tid * 8);
      __syncthreads();                        // drain vmcnt + barrier
      #pragma unroll
      for (int ki = 0; ki < 2; ki++) {
        int sl = ((ki * 4 + q) ^ (r & 7)) * 8;
        v8s a0 = *(const v8s*)&ldsA[r * 64 + sl];
        v8s a1 = *(const v8s*)&ldsA[(16 + r) * 64 + sl];
        v8s bb = *(const v8s*)&ldsB[(wid * 16 + r) * 64 + sl];
        acc0 = __builtin_amdgcn_mfma_f32_16x16x32_bf16(a0, bb, acc0, 0, 0, 0);
        acc1 = __builtin_amdgcn_mfma_f32_16x16x32_bf16(a1, bb, acc1, 0, 0, 0);
      }
    }
  }

  float* pp = parS + (size_t)kc * 32 * NPOS + n0;
  #pragma unroll
  for (int e = 0; e < 4; e++) {
    pp[(size_t)(q * 4 + e) * NPOS      + wid * 16 + r] = acc0[e];
    pp[(size_t)(16 + q * 4 + e) * NPOS + wid * 16 + r] = acc1[e];
  }
}

// ---------------- finalize: reduce 3 chunks, bias, sigmoid, coords -----------
// smp layout: [k][pos][{py,px,m}]
__global__ __launch_bounds__(256) void k_fin(const float* __restrict__ parS,
                                             const float* __restrict__ off_b,
                                             const float* __restrict__ mask_b,
                                             float* __restrict__ smp) {
  int k = blockIdx.x / 72;                    // 72 blocks per k (NPOS/256)
  int pos = (blockIdx.x % 72) * 256 + threadIdx.x;
  float s0 = 0.f, s1 = 0.f, s2 = 0.f;
  #pragma unroll
  for (int g = 0; g < 3; g++) {
    const float* pg = parS + (size_t)g * 32 * NPOS + pos;
    s0 += pg[(size_t)(2 * k)     * NPOS];
    s1 += pg[(size_t)(2 * k + 1) * NPOS];
    s2 += pg[(size_t)(18 + k)    * NPOS];
  }
  int hw = pos % 2304; int h = hw / 48, w = hw % 48;
  float m = 1.f / (1.f + expf(-(s2 + mask_b[k])));
  float* sp = smp + ((size_t)k * NPOS + pos) * 3;
  sp[0] = s0 + off_b[2 * k]     + (float)(k / 3) + (float)h - 1.f;
  sp[1] = s1 + off_b[2 * k + 1] + (float)(k % 3) + (float)w - 1.f;
  sp[2] = m;
}

// ---------------- fused deformable conv: register-direct gather --------------
// C[pos][cout] = sum_K gather(xT,smp)[pos][K] * wG[cout][K]
// A-operand (MFMA) = gathered val, built in REGISTERS (never touches LDS).
// B-operand = weights, double-buffered in LDS (16KB/buf), one barrier/step.
// Wave: 16 pos x 128 cout x full K. Block: 4 waves = 64 pos, one mt half.
// Grid 576 = 8 img(XCD) x 72; direct stores (no atomics, no out-zero).
// R10 bug fixed: xT gather channel excludes the tap component of K
// (tap selects the spatial row via smp, NOT an xT channel offset).
__global__ __launch_bounds__(256, 4) void k_fg(const unsigned short* __restrict__ wG,
                                               const unsigned short* __restrict__ xT,
                                               const float* __restrict__ smp,
                                               float* __restrict__ out) {
  __shared__ unsigned short ldsW[2][128 * 64];   // 2 x 16 KB
  int bid = blockIdx.x;                       // 576
  int b = bid & 7;                            // image == XCD
  int inner = bid >> 3;                       // 0..71
  int mt = inner & 1;                         // cout half
  int tid = threadIdx.x, lane = tid & 63, wid = tid >> 6;
  int ptile = (inner >> 1) * 4 + wid;         // 0..143 within image
  int r = lane & 15, q = lane >> 4;           // A-frag: row(pos)=r, k-chunk=q
  int pos = b * 2304 + ptile * 16 + r;
  const unsigned short* xb  = xT + (size_t)b * 2304 * 256;
  const unsigned short* wGm = wG + (size_t)mt * 128 * 2304;

  int srow = tid >> 3, sslot = tid & 7;       // weight staging coords
  int sxor = (sslot ^ (srow & 7)) * 8;        // pre-swizzled source slot

  v4f acc[8];
  #pragma unroll
  for (int i = 0; i < 8; i++) acc[i] = (v4f){0.f, 0.f, 0.f, 0.f};

  float wts0, wts1, wts2, wts3; int ro0, ro1, ro2, ro3;  // current tap
  float smy, smx, smm;                        // prefetched smp (next tap)
  v8s cor[8];                                 // in-flight corners (next step)
  v8s afc0, afc1;                             // current a_frags

  #define LOADSMP(tt) { const float* sp_ = smp + ((size_t)(tt) * NPOS + pos) * 3; \
                        smy = sp_[0]; smx = sp_[1]; smm = sp_[2]; }
  #define SETTAP() { \
    float y0f_ = floorf(smy), x0f_ = floorf(smx); \
    float wy_ = smy - y0f_, wx_ = smx - x0f_; \
    int y0_ = (int)y0f_, x0_ = (int)x0f_; \
    bool vy0_ = (y0_ >= 0) && (y0_ <= 47), vy1_ = (y0_ >= -1) && (y0_ <= 46); \
    bool vx0_ = (x0_ >= 0) && (x0_ <= 47), vx1_ = (x0_ >= -1) && (x0_ <= 46); \
    int yc0_ = min(max(y0_, 0), 47), yc1_ = min(max(y0_ + 1, 0), 47); \
    int xc0_ = min(max(x0_, 0), 47), xc1_ = min(max(x0_ + 1, 0), 47); \
    wts0 = (1.f - wy_) * (1.f - wx_) * smm * (float)(vy0_ && vx0_); \
    wts1 = (1.f - wy_) * wx_         * smm * (float)(vy0_ && vx1_); \
    wts2 = wy_         * (1.f - wx_) * smm * (float)(vy1_ && vx0_); \
    wts3 = wy_         * wx_         * smm * (float)(vy1_ && vx1_); \
    ro0 = yc0_ * 48 + xc0_; ro1 = yc0_ * 48 + xc1_; \
    ro2 = yc1_ * 48 + xc0_; ro3 = yc1_ * 48 + xc1_; }
  #define CORNER_ISSUE(ss) { int C0_ = ((ss) & 3) * 64 + q * 8; /* channel only! */ \
    _Pragma("unroll") for (int kk_ = 0; kk_ < 2; kk_++) { \
      cor[kk_ * 4 + 0] = *(const v8s*)&xb[ro0 * 256 + C0_ + kk_ * 32]; \
      cor[kk_ * 4 + 1] = *(const v8s*)&xb[ro1 * 256 + C0_ + kk_ * 32]; \
      cor[kk_ * 4 + 2] = *(const v8s*)&xb[ro2 * 256 + C0_ + kk_ * 32]; \
      cor[kk_ * 4 + 3] = *(const v8s*)&xb[ro3 * 256 + C0_ + kk_ * 32]; } }
  #define STAGE(bufi, ss) { int K0_ = ((ss) >> 2) * 256 + ((ss) & 3) * 64; \
    _Pragma("unroll") for (int rd_ = 0; rd_ < 4; rd_++) \
      gload16(wGm + (size_t)(rd_ * 32 + srow) * 2304 + K0_ + sxor, \
              &ldsW[bufi][rd_ * 2048 + tid * 8]); }
  #define AFRAG_BUILD() { \
    _Pragma("unroll") for (int kk_ = 0; kk_ < 2; kk_++) { \
      unsigned short vb8_[8]; \
      _Pragma("unroll") for (int i_ = 0; i_ < 8; i_++) { \
        float v_ = wts0 * bf2f((unsigned short)cor[kk_ * 4 + 0][i_]) \
                 + wts1 * bf2f((unsigned short)cor[kk_ * 4 + 1][i_]) \
                 + wts2 * bf2f((unsigned short)cor[kk_ * 4 + 2][i_]) \
                 + wts3 * bf2f((unsigned short)cor[kk_ * 4 + 3][i_]); \
        vb8_[i_] = f2bf(v_); } \
      if (kk_ == 0) afc0 = *(const v8s*)vb8_; else afc1 = *(const v8s*)vb8_; } }

  // ---- prologue: tap 0 setup, stage step 0, gather step 0
  LOADSMP(0);
  SETTAP();
  STAGE(0, 0);
  CORNER_ISSUE(0);
  LOADSMP(1);
  AFRAG_BUILD();                              // waits corners; afc = step 0
  __syncthreads();                            // buf0 staged (vmcnt drained)

  for (int s = 0; s < 36; s++) {
    int cur = s & 1, nxt = cur ^ 1;
    if (s < 35) {
      STAGE(nxt, s + 1);                      // weights for next step
      if (((s + 1) & 3) == 0) {               // next step starts a new tap
        SETTAP();                             // from prefetched smp
        if (((s + 1) >> 2) < 8) LOADSMP(((s + 1) >> 2) + 1);
      }
      CORNER_ISSUE(s + 1);                    // corners for next step
    }
    // ---- MFMA on current step: A from regs, B from LDS
    __builtin_amdgcn_s_setprio(1);
    #pragma unroll
    for (int kk = 0; kk < 2; kk++) {
      #pragma unroll
      for (int ct = 0; ct < 8; ct++) {
        v8s bfr = *(const v8s*)&ldsW[cur][(ct * 16 + r) * 64 + (((kk * 4 + q) ^ (r & 7)) * 8)];
        acc[ct] = __builtin_amdgcn_mfma_f32_16x16x32_bf16(
            (kk == 0 ? afc0 : afc1), bfr, acc[ct], 0, 0, 0);
      }
    }
    __builtin_amdgcn_s_setprio(0);
    if (s < 35) AFRAG_BUILD();                // corners have had MFMA-phase latency
    __syncthreads();                          // buffer swap point
  }

  // ---- epilogue: direct stores (exclusive ownership, no atomics)
  // D: col(lane&15)=cout offset, row(q*4+e)=pos offset -> dwordx4 per tile
  #pragma unroll
  for (int ct = 0; ct < 8; ct++) {
    int co = mt * 128 + ct * 16 + r;
    float* op = out + (size_t)b * (256 * 2304) + (size_t)co * 2304 + ptile * 16 + q * 4;
    *(v4f*)op = acc[ct];
  }
  #undef LOADSMP
  #undef SETTAP
  #undef CORNER_ISSUE
  #undef STAGE
  #undef AFRAG_BUILD
}

extern "C" void kernel_launch(void* const* d_in, const int* in_sizes, int n_in,
                              void* d_out, int out_size, void* d_ws, size_t ws_size,
                              hipStream_t stream) {
  const float* x      = (const float*)d_in[0];
  const float* weight = (const float*)d_in[1];
  const float* off_w  = (const float*)d_in[2];
  const float* off_b  = (const float*)d_in[3];
  const float* mask_w = (const float*)d_in[4];
  const float* mask_b = (const float*)d_in[5];
  float* out = (float*)d_out;
  char* ws = (char*)d_ws;

  unsigned short* xT   = (unsigned short*)(ws);             //  9,437,184 B -> 9,437,184
  unsigned short* wG   = (unsigned short*)(ws + 9437184);   //  1,179,648 B -> 10,616,832
  unsigned short* Wc2  = (unsigned short*)(ws + 10616832);  //    147,456 B -> 10,764,288
  unsigned short* zp   = (unsigned short*)(ws + 10764288);  //        512 B -> 10,764,800
  float*          smp  = (float*)(ws + 10764800);           //  1,990,656 B -> 12,755,456
  float*          parS = (float*)(ws + 12755456);           //  7,077,888 B -> 19,833,344

  hipLaunchKernelGGL(k_prep,   dim3(544),      dim3(256), 0, stream,
                     off_w, mask_w, weight, Wc2, zp, wG);
  hipLaunchKernelGGL(k_xt,     dim3(1152),     dim3(256), 0, stream, x, xT);
  hipLaunchKernelGGL(k_cg,     dim3(288, 3),   dim3(256), 0, stream, Wc2, xT, zp, parS);
  hipLaunchKernelGGL(k_fin,    dim3(648),      dim3(256), 0, stream, parS, off_b, mask_b, smp);
  hipLaunchKernelGGL(k_fg,     dim3(576),      dim3(256), 0, stream, wG, xT, smp, out);
}

// Round 12
// 95.044 us; speedup vs baseline: 1.4720x; 1.4720x over previous
//
#include <hip/hip_runtime.h>
#include <cstdint>
#include <cmath>

#define DEV __device__ __forceinline__

typedef float v4f __attribute__((ext_vector_type(4)));
typedef short v8s __attribute__((ext_vector_type(8)));
typedef short v4s __attribute__((ext_vector_type(4)));

// Problem constants
// x: [8,256,48,48] f32; weight: [256,256,3,3]; off_w: [18,256,3,3]; off_b:[18];
// mask_w: [9,256,3,3]; mask_b:[9]; out: [8,256,48,48] f32
static constexpr int HW    = 48 * 48;        // 2304
static constexpr int NPOS  = 8 * HW;         // 18432

DEV float bf2f(unsigned short u) {
  unsigned int v = ((unsigned int)u) << 16;
  float f; __builtin_memcpy(&f, &v, 4); return f;
}
DEV unsigned short f2bf(float f) {
  unsigned int u; __builtin_memcpy(&u, &f, 4);
  unsigned int r = (u + 0x7fffu + ((u >> 16) & 1u)) >> 16;
  return (unsigned short)r;
}

DEV void gload16(const void* g, void* l) {
  __builtin_amdgcn_global_load_lds(
      (const __attribute__((address_space(1))) unsigned int*)g,
      (__attribute__((address_space(3))) unsigned int*)l, 16, 0, 0);
}

// ---------------- prep (fused): Wc2 + zp; wG ---------------------------------
__global__ __launch_bounds__(256) void k_prep(const float* __restrict__ off_w,
                                              const float* __restrict__ mask_w,
                                              const float* __restrict__ weight,
                                              unsigned short* __restrict__ Wc2,
                                              unsigned short* __restrict__ zp,
                                              unsigned short* __restrict__ wG) {
  __shared__ float wrow[2304];
  int bid = blockIdx.x, tid = threadIdx.x;
  int i = bid * 256 + tid;
  if (bid < 288) {
    if (i < 256) zp[i] = 0;
    int o = i / 2304, col = i % 2304;
    int t = col >> 8, c = col & 255;
    float v = 0.f;
    if (o < 18)      v = off_w[(o * 256 + c) * 9 + t];
    else if (o < 27) v = mask_w[((o - 18) * 256 + c) * 9 + t];
    Wc2[i] = f2bf(v);
  } else {
    int co = bid - 288;
    const float* wsrc = weight + (size_t)co * 2304;
    for (int k = tid; k < 2304; k += 256) wrow[k] = wsrc[k];
    __syncthreads();
    unsigned short* dst = wG + (size_t)co * 2304;
    #pragma unroll
    for (int k = 0; k < 9; k++)
      dst[k * 256 + tid] = f2bf(wrow[tid * 9 + k]);
  }
}

// ---------------- prep: x NCHW f32 -> xT [b][hw][c] bf16 ---------------------
__global__ void k_xt(const float* __restrict__ x, unsigned short* __restrict__ xT) {
  __shared__ float tile[64][65];
  int bid = blockIdx.x;                 // b*144 + hwt*4 + ct
  int ct = bid & 3; int hwt = (bid >> 2) % 36; int b = bid / 144;
  int c0 = ct * 64, hw0 = hwt * 64;
  int tl = threadIdx.x & 63, tr = threadIdx.x >> 6;
  const float* xb = x + (size_t)(b * 256 + c0) * 2304 + hw0;
  #pragma unroll
  for (int r = 0; r < 16; r++) {
    int cr = tr + r * 4;
    tile[cr][tl] = xb[(size_t)cr * 2304 + tl];
  }
  __syncthreads();
  unsigned short* xo = xT + ((size_t)b * 2304 + hw0) * 256 + c0;
  #pragma unroll
  for (int r = 0; r < 16; r++) {
    int hr = tr + r * 4;
    xo[(size_t)hr * 256 + tl] = f2bf(tile[tl][hr]);
  }
}

// ---------------- offset/mask conv as MFMA GEMM ------------------------------
// S[32][NPOS] = Wc2[32][2304] * im2col(xT)[2304][NPOS], split-K by tap triple.
__global__ __launch_bounds__(256) void k_cg(const unsigned short* __restrict__ Wc2,
                                            const unsigned short* __restrict__ xT,
                                            const unsigned short* __restrict__ zp,
                                            float* __restrict__ parS) {
  __shared__ unsigned short ldsA[32 * 64];
  __shared__ unsigned short ldsB[64 * 64];
  int nt = blockIdx.x, kc = blockIdx.y;
  int n0 = nt * 64;
  int b = n0 / 2304, hw0 = n0 % 2304;         // BN=64 divides 2304: one image
  int tid = threadIdx.x, lane = tid & 63, wid = tid >> 6;
  int r = lane & 15, q = lane >> 4;
  int row0 = tid >> 3;                        // staging row (0..31)
  int sslot = (tid & 7) ^ (row0 & 7);         // pre-swizzled 16B slot

  int hwA = hw0 + row0,      hA = hwA / 48, wA = hwA % 48;   // B round 0 row
  int hwB = hw0 + row0 + 32, hB = hwB / 48, wB = hwB % 48;   // B round 1 row

  v4f acc0 = (v4f){0.f, 0.f, 0.f, 0.f};
  v4f acc1 = (v4f){0.f, 0.f, 0.f, 0.f};

  #pragma unroll
  for (int tt = 0; tt < 3; tt++) {
    int t = kc * 3 + tt;
    int dy = kc - 1, dx = tt - 1;
    int yA = hA + dy, xA = wA + dx;
    int yB = hB + dy, xB = wB + dx;
    bool vA = ((unsigned)yA < 48u) && ((unsigned)xA < 48u);
    bool vB = ((unsigned)yB < 48u) && ((unsigned)xB < 48u);
    const unsigned short* baseA2 = Wc2 + (size_t)row0 * 2304 + t * 256 + sslot * 8;
    const unsigned short* base0 = vA ? xT + ((size_t)(b * 2304 + yA * 48 + xA) * 256 + sslot * 8)
                                     : zp + sslot * 8;
    const unsigned short* base1 = vB ? xT + ((size_t)(b * 2304 + yB * 48 + xB) * 256 + sslot * 8)
                                     : zp + sslot * 8;
    #pragma unroll
    for (int cq = 0; cq < 4; cq++) {
      int c0s = cq * 64;
      __syncthreads();                        // prev tile reads done
      gload16(baseA2 + c0s, ldsA + tid * 8);
      gload16(base0  + c0s, ldsB + tid * 8);
      gload16(base1  + c0s, ldsB + 2048 + tid * 8);
      __syncthreads();                        // drain vmcnt + barrier
      #pragma unroll
      for (int ki = 0; ki < 2; ki++) {
        int sl = ((ki * 4 + q) ^ (r & 7)) * 8;
        v8s a0 = *(const v8s*)&ldsA[r * 64 + sl];
        v8s a1 = *(const v8s*)&ldsA[(16 + r) * 64 + sl];
        v8s bb = *(const v8s*)&ldsB[(wid * 16 + r) * 64 + sl];
        acc0 = __builtin_amdgcn_mfma_f32_16x16x32_bf16(a0, bb, acc0, 0, 0, 0);
        acc1 = __builtin_amdgcn_mfma_f32_16x16x32_bf16(a1, bb, acc1, 0, 0, 0);
      }
    }
  }

  float* pp = parS + (size_t)kc * 32 * NPOS + n0;
  #pragma unroll
  for (int e = 0; e < 4; e++) {
    pp[(size_t)(q * 4 + e) * NPOS      + wid * 16 + r] = acc0[e];
    pp[(size_t)(16 + q * 4 + e) * NPOS + wid * 16 + r] = acc1[e];
  }
}

// ---------------- finalize: reduce 3 chunks, bias, sigmoid, coords -----------
// smp layout: [k][pos][{py,px,m}]
__global__ __launch_bounds__(256) void k_fin(const float* __restrict__ parS,
                                             const float* __restrict__ off_b,
                                             const float* __restrict__ mask_b,
                                             float* __restrict__ smp) {
  int k = blockIdx.x / 72;                    // 72 blocks per k (NPOS/256)
  int pos = (blockIdx.x % 72) * 256 + threadIdx.x;
  float s0 = 0.f, s1 = 0.f, s2 = 0.f;
  #pragma unroll
  for (int g = 0; g < 3; g++) {
    const float* pg = parS + (size_t)g * 32 * NPOS + pos;
    s0 += pg[(size_t)(2 * k)     * NPOS];
    s1 += pg[(size_t)(2 * k + 1) * NPOS];
    s2 += pg[(size_t)(18 + k)    * NPOS];
  }
  int hw = pos % 2304; int h = hw / 48, w = hw % 48;
  float m = 1.f / (1.f + expf(-(s2 + mask_b[k])));
  float* sp = smp + ((size_t)k * NPOS + pos) * 3;
  sp[0] = s0 + off_b[2 * k]     + (float)(k / 3) + (float)h - 1.f;
  sp[1] = s1 + off_b[2 * k + 1] + (float)(k % 3) + (float)w - 1.f;
  sp[2] = m;
}

// ---------------- deformable im2col v2: val[pos][k*256+c] bf16 ---------------
// One wave per (pos,tap); lane owns 4 channels. Corner loads are dwordx2
// (512B/corner/wave, fully coalesced: xT rows are 512B). XCD i owns image i
// (xT slice 1.2MB -> L2-resident). 41472 blocks -> full-occupancy TLP hides
// the irregular gather latency (the thing no fused variant could do).
__global__ __launch_bounds__(256) void k_gather(const unsigned short* __restrict__ xT,
                                                const float* __restrict__ smp,
                                                unsigned short* __restrict__ val) {
  int raw = blockIdx.x;                       // 41472 = 8 img x 5184
  int b = raw & 7;                            // image == XCD
  int it = raw >> 3;                          // 0..5183
  int wv = threadIdx.x >> 6, lane = threadIdx.x & 63;
  int task = it * 4 + wv;                     // 0..20735 within image
  int k = task % 9, hw = task / 9;
  int pos = b * 2304 + hw;
  const float* sp = smp + ((size_t)k * NPOS + pos) * 3;
  float py = sp[0], px = sp[1], m = sp[2];
  float y0f = floorf(py), x0f = floorf(px);
  float wy = py - y0f, wx = px - x0f;
  int y0 = (int)y0f, x0 = (int)x0f;
  bool vy0 = (y0 >= 0) && (y0 <= 47), vy1 = (y0 >= -1) && (y0 <= 46);
  bool vx0 = (x0 >= 0) && (x0 <= 47), vx1 = (x0 >= -1) && (x0 <= 46);
  int yc0 = min(max(y0, 0), 47), yc1 = min(max(y0 + 1, 0), 47);
  int xc0 = min(max(x0, 0), 47), xc1 = min(max(x0 + 1, 0), 47);
  float w00 = (1.f - wy) * (1.f - wx) * m * (float)(vy0 && vx0);
  float w01 = (1.f - wy) * wx         * m * (float)(vy0 && vx1);
  float w10 = wy         * (1.f - wx) * m * (float)(vy1 && vx0);
  float w11 = wy         * wx         * m * (float)(vy1 && vx1);
  const unsigned short* xb = xT + (size_t)b * 2304 * 256;
  int ch = lane * 4;
  v4s c00 = *(const v4s*)&xb[(yc0 * 48 + xc0) * 256 + ch];
  v4s c01 = *(const v4s*)&xb[(yc0 * 48 + xc1) * 256 + ch];
  v4s c10 = *(const v4s*)&xb[(yc1 * 48 + xc0) * 256 + ch];
  v4s c11 = *(const v4s*)&xb[(yc1 * 48 + xc1) * 256 + ch];
  unsigned short o[4];
  #pragma unroll
  for (int i = 0; i < 4; i++) {
    float v = w00 * bf2f((unsigned short)c00[i]) + w01 * bf2f((unsigned short)c01[i])
            + w10 * bf2f((unsigned short)c10[i]) + w11 * bf2f((unsigned short)c11[i]);
    o[i] = f2bf(v);
  }
  *(v4s*)&val[(size_t)pos * 2304 + k * 256 + ch] = *(const v4s*)o;
}

// ---------------- main GEMM: C[co][n] = sum_K wG[co][K] * val[n][K] ----------
// M=256 (2 tiles of 128), N=18432 (288 tiles of 64), K=2304, BK=64.
// R3 structure + both-sides XOR swizzle (zero-conflict pattern proven in
// k_cg/k_fg) + XCD swizzle (image == XCD; mt pairs adjacent for val L2 reuse).
__global__ __launch_bounds__(256) void k_gemm(const unsigned short* __restrict__ wG,
                                              const unsigned short* __restrict__ val,
                                              float* __restrict__ out) {
  __shared__ unsigned short ldsA[128 * 64];   // 16 KB, swizzled slots
  __shared__ unsigned short ldsB[64 * 64];    //  8 KB, swizzled slots
  int raw = blockIdx.x;                       // 576 = 8 xcd x 72
  int xcd = raw & 7, idx = raw >> 3;          // idx 0..71
  int mt = idx & 1;
  int nt = xcd * 36 + (idx >> 1);             // image == xcd
  int co0 = mt * 128, n0 = nt * 64;
  int tid = threadIdx.x, lane = tid & 63, wid = tid >> 6;
  int wm = wid >> 1, wn = wid & 1;            // 2x2 waves, wave tile 64x32
  int r = lane & 15, q = lane >> 4;
  int srow = tid >> 3;                        // staging row 0..31
  int sx = ((tid & 7) ^ (srow & 7)) * 8;      // pre-swizzled source slot

  const unsigned short* Ag = wG  + (size_t)(co0 + srow) * 2304 + sx;
  const unsigned short* Bg = val + (size_t)(n0  + srow) * 2304 + sx;

  v4f acc[4][2];
  #pragma unroll
  for (int i = 0; i < 4; i++)
    #pragma unroll
    for (int j = 0; j < 2; j++) acc[i][j] = (v4f){0.f, 0.f, 0.f, 0.f};

  for (int ks = 0; ks < 36; ks++) {
    int k0 = ks * 64;
    __syncthreads();                          // all reads of prev tile done
    #pragma unroll
    for (int i = 0; i < 4; i++)               // A: 16KB = 4 rounds (rows i*32+srow)
      gload16(Ag + k0 + (size_t)i * 32 * 2304, ldsA + i * 2048 + tid * 8);
    #pragma unroll
    for (int i = 0; i < 2; i++)               // B: 8KB = 2 rounds
      gload16(Bg + k0 + (size_t)i * 32 * 2304, ldsB + i * 2048 + tid * 8);
    __syncthreads();                          // compiler drains vmcnt before barrier
    #pragma unroll
    for (int ki = 0; ki < 2; ki++) {
      int sl = ((ki * 4 + q) ^ (r & 7)) * 8;  // swizzled read slot
      v8s af[4], bf[2];
      #pragma unroll
      for (int fm = 0; fm < 4; fm++)
        af[fm] = *(const v8s*)&ldsA[(wm * 64 + fm * 16 + r) * 64 + sl];
      #pragma unroll
      for (int fn = 0; fn < 2; fn++)
        bf[fn] = *(const v8s*)&ldsB[(wn * 32 + fn * 16 + r) * 64 + sl];
      #pragma unroll
      for (int fm = 0; fm < 4; fm++)
        #pragma unroll
        for (int fn = 0; fn < 2; fn++)
          acc[fm][fn] = __builtin_amdgcn_mfma_f32_16x16x32_bf16(af[fm], bf[fn], acc[fm][fn], 0, 0, 0);
    }
  }

  int bimg = n0 / 2304, hw0 = n0 % 2304;      // BN=64 divides 2304: single image
  float* op = out + (size_t)bimg * (256 * 2304) + hw0;
  #pragma unroll
  for (int fm = 0; fm < 4; fm++) {
    int co = co0 + wm * 64 + fm * 16 + q * 4;
    #pragma unroll
    for (int fn = 0; fn < 2; fn++) {
      int nn = wn * 32 + fn * 16 + r;
      #pragma unroll
      for (int e = 0; e < 4; e++)
        op[(size_t)(co + e) * 2304 + nn] = acc[fm][fn][e];
    }
  }
}

extern "C" void kernel_launch(void* const* d_in, const int* in_sizes, int n_in,
                              void* d_out, int out_size, void* d_ws, size_t ws_size,
                              hipStream_t stream) {
  const float* x      = (const float*)d_in[0];
  const float* weight = (const float*)d_in[1];
  const float* off_w  = (const float*)d_in[2];
  const float* off_b  = (const float*)d_in[3];
  const float* mask_w = (const float*)d_in[4];
  const float* mask_b = (const float*)d_in[5];
  float* out = (float*)d_out;
  char* ws = (char*)d_ws;

  unsigned short* xT   = (unsigned short*)(ws);             //  9,437,184 B -> 9,437,184
  unsigned short* wG   = (unsigned short*)(ws + 9437184);   //  1,179,648 B -> 10,616,832
  unsigned short* Wc2  = (unsigned short*)(ws + 10616832);  //    147,456 B -> 10,764,288
  unsigned short* zp   = (unsigned short*)(ws + 10764288);  //        512 B -> 10,764,800
  float*          smp  = (float*)(ws + 10764800);           //  1,990,656 B -> 12,755,456
  float*          parS = (float*)(ws + 12755456);           //  7,077,888 B -> 19,833,344
  unsigned short* val  = (unsigned short*)(ws + 12755456);  // overlaps parS (dead after k_fin)
                                                            // 84,934,656 B -> 97,690,112

  hipLaunchKernelGGL(k_prep,   dim3(544),      dim3(256), 0, stream,
                     off_w, mask_w, weight, Wc2, zp, wG);
  hipLaunchKernelGGL(k_xt,     dim3(1152),     dim3(256), 0, stream, x, xT);
  hipLaunchKernelGGL(k_cg,     dim3(288, 3),   dim3(256), 0, stream, Wc2, xT, zp, parS);
  hipLaunchKernelGGL(k_fin,    dim3(648),      dim3(256), 0, stream, parS, off_b, mask_b, smp);
  hipLaunchKernelGGL(k_gather, dim3(41472),    dim3(256), 0, stream, xT, smp, val);
  hipLaunchKernelGGL(k_gemm,   dim3(576),      dim3(256), 0, stream, wG, val, out);
}